// Round 5
// baseline (458.730 us; speedup 1.0000x reference)
//
#include <hip/hip_runtime.h>

#define D 128

// round-to-nearest-even f32 -> bf16 (finite inputs only)
__device__ __forceinline__ unsigned int f2bf_u(float f) {
    unsigned int u = __float_as_uint(f);
    return (u + 0x7fffu + ((u >> 16) & 1u)) >> 16;
}
__device__ __forceinline__ unsigned short f2bf(float f) {
    return (unsigned short)f2bf_u(f);
}
__device__ __forceinline__ unsigned int pack2(float a, float b) {
    return f2bf_u(a) | (f2bf_u(b) << 16);
}
__device__ __forceinline__ float blo(unsigned int u) { return __uint_as_float(u << 16); }
__device__ __forceinline__ float bhi(unsigned int u) { return __uint_as_float(u & 0xffff0000u); }

// ---------------- GEMM: h[i][c] = bf16( b[c] + sum_k x[i][k] * W[c][k] ) ----
// LDS: 32 KB (W, bf16-pair packed, transposed) + 16 KB (x tile, bf16-pair) = 48 KB
__global__ __launch_bounds__(512) void gemm_kernel(
    const float* __restrict__ x, const float* __restrict__ W,
    const float* __restrict__ bias, unsigned short* __restrict__ h, int n) {
    __shared__ unsigned int Wu[64 * 128];  // Wu[kk*128+c] = bf16(W[c][2kk]) | bf16(W[c][2kk+1])<<16
    __shared__ unsigned int Xu[64 * 64];   // Xu[r*64+kk]  = bf16(x[r0+r][2kk]) | bf16(x[r0+r][2kk+1])<<16
    const int t = threadIdx.x;
    const int c = t & 127;
    const int g = t >> 7;  // 0..3

    // stage W transposed+packed: thread (c,g) loads W[c][g*32 .. g*32+31]
    const float4* W4 = reinterpret_cast<const float4*>(W);
#pragma unroll
    for (int q = 0; q < 8; ++q) {
        float4 w = W4[c * 32 + g * 8 + q];
        const int kk = g * 16 + q * 2;
        Wu[(kk + 0) * 128 + c] = pack2(w.x, w.y);
        Wu[(kk + 1) * 128 + c] = pack2(w.z, w.w);
    }
    // stage 64 rows of x (coalesced float4 -> packed bf16 pairs)
    const int r0 = blockIdx.x * 64;
    const float4* x4 = reinterpret_cast<const float4*>(x);
    const float4 z4 = make_float4(0.f, 0.f, 0.f, 0.f);
#pragma unroll
    for (int q = 0; q < 4; ++q) {
        const int f = q * 512 + t;           // f = r*32 + kq
        const int r = f >> 5, kq = f & 31;   // kq = float4 index within row
        float4 v = (r0 + r < n) ? x4[(size_t)(r0 + r) * 32 + kq] : z4;
        Xu[r * 64 + kq * 2 + 0] = pack2(v.x, v.y);
        Xu[r * 64 + kq * 2 + 1] = pack2(v.z, v.w);
    }
    __syncthreads();

    const float bc = bias[c];
#pragma unroll 1
    for (int rr = 0; rr < 16; rr += 4) {
        const int r = g * 16 + rr;
        const unsigned int* xp0 = &Xu[(r + 0) * 64];
        const unsigned int* xp1 = &Xu[(r + 1) * 64];
        const unsigned int* xp2 = &Xu[(r + 2) * 64];
        const unsigned int* xp3 = &Xu[(r + 3) * 64];
        float a0 = bc, a1 = bc, a2 = bc, a3 = bc;
#pragma unroll 8
        for (int kk = 0; kk < 64; ++kk) {
            const unsigned int wp = Wu[kk * 128 + c];
            const float w0 = blo(wp), w1 = bhi(wp);
            const unsigned int u0 = xp0[kk];
            const unsigned int u1 = xp1[kk];
            const unsigned int u2 = xp2[kk];
            const unsigned int u3 = xp3[kk];
            a0 = fmaf(blo(u0), w0, fmaf(bhi(u0), w1, a0));
            a1 = fmaf(blo(u1), w0, fmaf(bhi(u1), w1, a1));
            a2 = fmaf(blo(u2), w0, fmaf(bhi(u2), w1, a2));
            a3 = fmaf(blo(u3), w0, fmaf(bhi(u3), w1, a3));
        }
        const int row = r0 + r;
        if (row + 0 < n) h[(size_t)(row + 0) * 128 + c] = f2bf(a0);
        if (row + 1 < n) h[(size_t)(row + 1) * 128 + c] = f2bf(a1);
        if (row + 2 < n) h[(size_t)(row + 2) * 128 + c] = f2bf(a2);
        if (row + 3 < n) h[(size_t)(row + 3) * 128 + c] = f2bf(a3);
    }
}

// ---------------- CSR build ------------------------------------------------
__global__ void hist_kernel(const int* __restrict__ row, int* __restrict__ cnt, int ne) {
    int i = blockIdx.x * 256 + threadIdx.x;
    if (i < ne) atomicAdd(&cnt[row[i]], 1);
}

__global__ __launch_bounds__(1024) void scan1_kernel(
    const int* __restrict__ cnt, int* __restrict__ incl, int* __restrict__ bsum, int n) {
    __shared__ int lds[1024];
    const int tid = threadIdx.x;
    const int i = blockIdx.x * 1024 + tid;
    int v = (i < n) ? cnt[i] : 0;
    lds[tid] = v;
    __syncthreads();
    for (int off = 1; off < 1024; off <<= 1) {
        int a = (tid >= off) ? lds[tid - off] : 0;
        __syncthreads();
        lds[tid] += a;
        __syncthreads();
    }
    if (i < n) incl[i] = lds[tid];
    if (tid == 1023) bsum[blockIdx.x] = lds[1023];
}

__global__ void scan2_kernel(int* __restrict__ bsum, int nb) {
    __shared__ int lds[128];
    const int tid = threadIdx.x;
    int v = (tid < nb) ? bsum[tid] : 0;
    lds[tid] = v;
    __syncthreads();
    for (int off = 1; off < 128; off <<= 1) {
        int a = (tid >= off) ? lds[tid - off] : 0;
        __syncthreads();
        lds[tid] += a;
        __syncthreads();
    }
    if (tid < nb) bsum[tid] = lds[tid] - v;  // exclusive
}

__global__ __launch_bounds__(1024) void scan3_kernel(
    const int* __restrict__ cnt, const int* __restrict__ incl,
    const int* __restrict__ bsum, int* __restrict__ rs, int* __restrict__ cur, int n) {
    const int i = blockIdx.x * 1024 + threadIdx.x;
    if (i < n) {
        int excl = bsum[blockIdx.x] + incl[i] - cnt[i];
        rs[i] = excl;
        cur[i] = excl;
        if (i == n - 1) rs[n] = bsum[blockIdx.x] + incl[i];
    }
}

__global__ void scatter_kernel(const int* __restrict__ row, const int* __restrict__ col,
                               int* __restrict__ cur, int* __restrict__ scol, int ne) {
    int i = blockIdx.x * 256 + threadIdx.x;
    if (i < ne) {
        int r = row[i];
        int p = atomicAdd(&cur[r], 1);
        scol[p] = col[i];
    }
}

// ---------------- Aggregate: out[i] = relu((h[i] + sum_nb h[col]) / deg) ---
// f32 output: lane handles channels (2*lane, 2*lane+1), writes one float2.
__global__ __launch_bounds__(256) void GraphConv_88364657147964_kernel(
    const unsigned int* __restrict__ h32, const int* __restrict__ rs,
    const int* __restrict__ scol, float2* __restrict__ out, int n) {
    const int lane = threadIdx.x & 63;
    const int wid = (blockIdx.x << 2) + (threadIdx.x >> 6);  // node id (1 wave/node)
    if (wid >= n) return;
    const int s = rs[wid], e = rs[wid + 1];
    const int cnt = e - s;
    unsigned int v = h32[(size_t)wid * 64 + lane];  // self loop
    float acc0 = blo(v);
    float acc1 = bhi(v);
    for (int base = 0; base < cnt; base += 64) {
        const int m = min(64, cnt - base);
        int cidx = 0;
        if (base + lane < cnt) cidx = scol[s + base + lane];
        int j = 0;
        for (; j + 4 <= m; j += 4) {
            int c0 = __shfl(cidx, j + 0);
            int c1 = __shfl(cidx, j + 1);
            int c2 = __shfl(cidx, j + 2);
            int c3 = __shfl(cidx, j + 3);
            unsigned int v0 = h32[(size_t)c0 * 64 + lane];
            unsigned int v1 = h32[(size_t)c1 * 64 + lane];
            unsigned int v2 = h32[(size_t)c2 * 64 + lane];
            unsigned int v3 = h32[(size_t)c3 * 64 + lane];
            acc0 += blo(v0); acc1 += bhi(v0);
            acc0 += blo(v1); acc1 += bhi(v1);
            acc0 += blo(v2); acc1 += bhi(v2);
            acc0 += blo(v3); acc1 += bhi(v3);
        }
        for (; j < m; ++j) {
            int cj = __shfl(cidx, j);
            unsigned int vj = h32[(size_t)cj * 64 + lane];
            acc0 += blo(vj);
            acc1 += bhi(vj);
        }
    }
    const float inv = 1.0f / (float)(cnt + 1);  // deg = incoming edges + self loop
    acc0 = fmaxf(acc0 * inv, 0.0f);
    acc1 = fmaxf(acc1 * inv, 0.0f);
    out[(size_t)wid * 64 + lane] = make_float2(acc0, acc1);
}

// ---------------------------------------------------------------------------
extern "C" void kernel_launch(void* const* d_in, const int* in_sizes, int n_in,
                              void* d_out, int out_size, void* d_ws, size_t ws_size,
                              hipStream_t stream) {
    const float* x = (const float*)d_in[0];
    const float* W = (const float*)d_in[1];
    const float* b = (const float*)d_in[2];
    const int* erow = (const int*)d_in[3];
    const int* ecol = (const int*)d_in[4];
    const int n = in_sizes[0] / D;   // 100000
    const int ne = in_sizes[3];      // 1600000

    char* ws = (char*)d_ws;
    size_t off = 0;
    auto alloc = [&](size_t bytes) -> void* {
        off = (off + 15) & ~(size_t)15;
        void* p = ws + off;
        off += bytes;
        return p;
    };
    unsigned short* h = (unsigned short*)alloc((size_t)n * D * 2);  // 25.6 MB bf16
    int* cnt  = (int*)alloc((size_t)n * 4);
    int* incl = (int*)alloc((size_t)n * 4);
    int* rs   = (int*)alloc(((size_t)n + 1) * 4);
    int* cur  = (int*)alloc((size_t)n * 4);
    int* scol = (int*)alloc((size_t)ne * 4);
    const int nb = (n + 1023) / 1024;  // 98 scan blocks
    int* bsum = (int*)alloc((size_t)nb * 4);

    hipMemsetAsync(cnt, 0, (size_t)n * 4, stream);
    gemm_kernel<<<(n + 63) / 64, 512, 0, stream>>>(x, W, b, h, n);
    hist_kernel<<<(ne + 255) / 256, 256, 0, stream>>>(erow, cnt, ne);
    scan1_kernel<<<nb, 1024, 0, stream>>>(cnt, incl, bsum, n);
    scan2_kernel<<<1, 128, 0, stream>>>(bsum, nb);
    scan3_kernel<<<nb, 1024, 0, stream>>>(cnt, incl, bsum, rs, cur, n);
    scatter_kernel<<<(ne + 255) / 256, 256, 0, stream>>>(erow, ecol, cur, scol, ne);
    GraphConv_88364657147964_kernel<<<(n + 3) / 4, 256, 0, stream>>>(
        (const unsigned int*)h, rs, scol, (float2*)d_out, n);
}